// Round 3
// baseline (1332.844 us; speedup 1.0000x reference)
//
#include <hip/hip_runtime.h>
#include <math.h>

#define B_    4
#define HW_   4800
#define K_    8
#define IMGD  192
#define PTD   128
#define NH_   6
#define DH_   64
#define INNER 384
#define KVIN  154     // PTD + 26 pos dims
#define QT    8       // queries per block (kernel 2)
#define NJ    64      // QT * K_
#define XLD   155     // padded LDS stride for X rows (odd -> bank-friendly)

// ---------------------------------------------------------------------------
// Kernel 1: brute-force kNN. One 64-lane wave per query.
// Distance replicates the reference's f32 BLAS-path arithmetic:
//   d2 = round(sqq + sqp) - 2*dot,  dot = fma(qy,py, round(qx*px))
// (jnp.einsum -> sgemm/XLA dot: K=2 accumulated with FMA, ascending k.
//  Plain no-FMA f32 (r2) and exact f64 (r1) both leave flipped queries.)
// Ties break by lower index (lax.top_k semantics).
// ---------------------------------------------------------------------------
__global__ __launch_bounds__(256) void knn_kernel(
    const float* __restrict__ proj_uv,   // [B][HW][2]
    const float* __restrict__ img_uv,    // [HW][2]
    int* __restrict__ idx_out)           // [B][HW][K]
{
#pragma clang fp contract(off)
  __shared__ float s_px[HW_];
  __shared__ float s_py[HW_];
  __shared__ float s_cd[256][K_];
  __shared__ int   s_ci[256][K_];

  const int tid  = threadIdx.x;
  const int wave = tid >> 6;
  const int lane = tid & 63;
  const int blk  = blockIdx.x;               // 0..4799
  const int b    = blk / (HW_ / 4);
  const int q    = (blk % (HW_ / 4)) * 4 + wave;

  const float2* pv = reinterpret_cast<const float2*>(proj_uv + (size_t)b * HW_ * 2);
  for (int i = tid; i < HW_; i += 256) {
    float2 p = pv[i];
    s_px[i] = p.x; s_py[i] = p.y;
  }
  __syncthreads();

  const float qx = img_uv[q * 2 + 0];
  const float qy = img_uv[q * 2 + 1];
  const float sqq = qx * qx + qy * qy;       // square-then-sum, no fma (pragma)

  float dist[K_];
  int   ind[K_];
#pragma unroll
  for (int s = 0; s < K_; ++s) { dist[s] = 3.4e38f; ind[s] = 0x7fffffff; }

  // each lane scans 75 candidates, keeps sorted top-8 (static indices only)
  for (int n = lane; n < HW_; n += 64) {
    const float px = s_px[n], py = s_py[n];
    const float sqp = px * px + py * py;     // f32 no fma
    const float dot = fmaf(qy, py, qx * px); // BLAS K=2: fma ascending k
    const float d   = (sqq + sqp) - 2.0f * dot;
    if (d < dist[K_ - 1]) {
      bool placed = false;
#pragma unroll
      for (int s = K_ - 1; s >= 1; --s) {
        if (!placed) {
          if (d < dist[s - 1]) { dist[s] = dist[s - 1]; ind[s] = ind[s - 1]; }
          else                 { dist[s] = d; ind[s] = n; placed = true; }
        }
      }
      if (!placed) { dist[0] = d; ind[0] = n; }
    }
  }

  // spill sorted lists to LDS so the head pointer can be a dynamic index
#pragma unroll
  for (int s = 0; s < K_; ++s) { s_cd[tid][s] = dist[s]; s_ci[tid][s] = ind[s]; }

  int p = 0;
#pragma unroll
  for (int r = 0; r < K_; ++r) {
    float hd = (p < K_) ? s_cd[tid][p] : 3.4e38f;
    int   hi = (p < K_) ? s_ci[tid][p] : 0x7fffffff;
    float bd = hd; int bi = hi;
#pragma unroll
    for (int m = 1; m < 64; m <<= 1) {
      float od = __shfl_xor(bd, m);
      int   oi = __shfl_xor(bi, m);
      if (od < bd || (od == bd && oi < bi)) { bd = od; bi = oi; }
    }
    if (hd == bd && hi == bi) p++;           // winner pops its head
    if (lane == r) idx_out[((size_t)b * HW_ + q) * K_ + r] = bi;
  }
}

// ---------------------------------------------------------------------------
// Kernel 2: fully fused per-query-tile pipeline. 256 threads, 8 queries/block.
// LDS aliasing: s_regB = {LN rows | xbar chunk}, s_regA = {q_normed | attn_out}
// ---------------------------------------------------------------------------
__global__ __launch_bounds__(256) void fused_kernel(
    const float* __restrict__ feat_2d,
    const float* __restrict__ feat_3d,
    const float* __restrict__ img_uv,
    const float* __restrict__ ln_gamma,
    const float* __restrict__ q_gamma,
    const float* __restrict__ k_gamma,
    const float* __restrict__ Wq,     // [192][384]
    const float* __restrict__ Wkv,    // [154][768]
    const float* __restrict__ Wout,   // [384][384]
    const int*   __restrict__ idx_ws,
    float* __restrict__ out)          // [B][HW][384]
{
  __shared__ float s_X[NJ][XLD];          // 64 kv-input rows (154 used)
  __shared__ float s_regA[QT][INNER];     // qn, later attn_out
  __shared__ float s_regB[24 * XLD];      // ln rows (8x192), later xbar (24x155)
  __shared__ float s_scores[NJ][NH_];
  __shared__ float s_attn[QT][NH_][K_];
  __shared__ float s_mask[NJ];
  __shared__ int   s_idx[NJ];
  __shared__ float s_offx[NJ];
  __shared__ float s_offy[NJ];
  __shared__ float s_norm[QT * NH_];

  const int tid = threadIdx.x;
  const int b   = blockIdx.y;
  const int q0  = blockIdx.x * QT;

  // ---- P0: gather indices, offsets, mask (mask margins >=2.5e-4, any prec ok)
  if (tid < NJ) {
    const int j  = tid;
    const int q  = q0 + (j >> 3);
    const int id = idx_ws[((size_t)b * HW_ + q) * K_ + (j & 7)];
    s_idx[j] = id;
    const float ax = img_uv[id * 2], ay = img_uv[id * 2 + 1];
    const float bx = img_uv[q * 2],  by = img_uv[q * 2 + 1];
    s_offx[j] = ax - bx; s_offy[j] = ay - by;
    const double dox = (double)ax - (double)bx;
    const double doy = (double)ay - (double)by;
    s_mask[j] = (dox * dox + doy * doy <= 0.010000000000000002) ? 1.f : 0.f;
  }

  // ---- P1: LayerNorm of 8 feat_2d rows (32 lanes per row)
  {
    const int r  = ((tid >> 6) << 1) | ((tid >> 5) & 1);
    const int sl = tid & 31;
    const float* row = feat_2d + ((size_t)b * HW_ + q0 + r) * IMGD;
    float x[6]; float sum = 0.f, ssq = 0.f;
#pragma unroll
    for (int i = 0; i < 6; ++i) { x[i] = row[sl + 32 * i]; sum += x[i]; ssq += x[i] * x[i]; }
#pragma unroll
    for (int m = 16; m >= 1; m >>= 1) { sum += __shfl_xor(sum, m); ssq += __shfl_xor(ssq, m); }
    const float mu = sum * (1.f / 192.f);
    float var = ssq * (1.f / 192.f) - mu * mu;
    var = fmaxf(var, 0.f);
    const float rstd = rsqrtf(var + 1e-5f);
    float* lnr = s_regB + r * IMGD;
#pragma unroll
    for (int i = 0; i < 6; ++i) {
      const int c = sl + 32 * i;
      lnr[c] = (x[i] - mu) * rstd * ln_gamma[c];
    }
  }
  __syncthreads();

  // ---- P2: Q projection (each thread: 1 row, 12 contiguous cols)
  {
    const int r  = tid >> 5;
    const int c0 = (tid & 31) * 12;
    const float* lnr = s_regB + r * IMGD;
    float acc[12];
#pragma unroll
    for (int i = 0; i < 12; ++i) acc[i] = 0.f;
    for (int kk = 0; kk < IMGD; ++kk) {
      const float xv = lnr[kk];
      const float4* wp = reinterpret_cast<const float4*>(Wq + (size_t)kk * INNER + c0);
      const float4 w0 = wp[0], w1 = wp[1], w2 = wp[2];
      acc[0] += xv * w0.x; acc[1] += xv * w0.y; acc[2]  += xv * w0.z; acc[3]  += xv * w0.w;
      acc[4] += xv * w1.x; acc[5] += xv * w1.y; acc[6]  += xv * w1.z; acc[7]  += xv * w1.w;
      acc[8] += xv * w2.x; acc[9] += xv * w2.y; acc[10] += xv * w2.z; acc[11] += xv * w2.w;
    }
#pragma unroll
    for (int i = 0; i < 12; ++i) s_regA[r][c0 + i] = acc[i];
  }
  // ---- P3: build X rows (feat_3d gather + harmonic pos emb), same region
  {
    const int j    = tid >> 2;
    const int tsub = tid & 3;
    const int id   = s_idx[j];
    const float* f3 = feat_3d + ((size_t)b * HW_ + id) * PTD;
    const float4* f4 = reinterpret_cast<const float4*>(f3) + tsub * 8;
    float* xr = s_X[j];
#pragma unroll
    for (int i = 0; i < 8; ++i) {
      const float4 v = f4[i];
      const int c = tsub * 32 + i * 4;
      xr[c] = v.x; xr[c + 1] = v.y; xr[c + 2] = v.z; xr[c + 3] = v.w;
    }
    if (tsub == 0) {
      const float ox = s_offx[j], oy = s_offy[j];
#pragma unroll
      for (int m = 0; m < 6; ++m) {
        const float fr = (float)(1 << m);
        float sx, cx, sy, cy;
        sincosf(ox * fr, &sx, &cx);
        sincosf(oy * fr, &sy, &cy);
        xr[128 + m] = sx; xr[134 + m] = sy;   // sin(ox*f),   sin(oy*f)
        xr[140 + m] = cx; xr[146 + m] = cy;   // cos(ox*f),   cos(oy*f)
      }
      xr[152] = ox; xr[153] = oy;
    }
  }
  __syncthreads();

  // ---- P2b: q RMSNorm
  if (tid < QT * NH_) {
    const int r = tid / NH_, h = tid % NH_;
    const float* v = &s_regA[r][h * DH_];
    float ss = 0.f;
#pragma unroll
    for (int d = 0; d < DH_; ++d) ss += v[d] * v[d];
    s_norm[tid] = fmaxf(sqrtf(ss), 1e-12f);
  }
  __syncthreads();
  {
    const int r  = tid >> 5;
    const int c0 = (tid & 31) * 12;
#pragma unroll
    for (int i = 0; i < 12; ++i) {
      const int c = c0 + i;
      const float n = s_norm[r * NH_ + (c >> 6)];
      s_regA[r][c] *= (8.f / n) * q_gamma[c];
    }
  }
  __syncthreads();

  // ---- P4: K-part GEMM (64x384 = X @ Wk) + fused k-RMSNorm + scores
  {
    const int tc = tid & 15;
    const int tj = tid >> 4;
    const int j0 = tj * 4;
    const int r  = tj >> 1;          // all 4 rows j0..j0+3 share query row r
    for (int h = 0; h < NH_; ++h) {
      const int cb = h * DH_ + tc * 4;
      float acc[4][4];
#pragma unroll
      for (int a = 0; a < 4; ++a)
#pragma unroll
        for (int i = 0; i < 4; ++i) acc[a][i] = 0.f;
      for (int kk = 0; kk < KVIN; ++kk) {
        const float4 w = *reinterpret_cast<const float4*>(Wkv + (size_t)kk * (2 * INNER) + cb);
#pragma unroll
        for (int a = 0; a < 4; ++a) {
          const float xv = s_X[j0 + a][kk];
          acc[a][0] += xv * w.x; acc[a][1] += xv * w.y;
          acc[a][2] += xv * w.z; acc[a][3] += xv * w.w;
        }
      }
      const float g0 = k_gamma[cb + 0], g1 = k_gamma[cb + 1];
      const float g2 = k_gamma[cb + 2], g3 = k_gamma[cb + 3];
      const float q0v = s_regA[r][cb + 0], q1v = s_regA[r][cb + 1];
      const float q2v = s_regA[r][cb + 2], q3v = s_regA[r][cb + 3];
      float ss[4], sc[4];
#pragma unroll
      for (int a = 0; a < 4; ++a) {
        ss[a] = acc[a][0] * acc[a][0] + acc[a][1] * acc[a][1]
              + acc[a][2] * acc[a][2] + acc[a][3] * acc[a][3];
        sc[a] = acc[a][0] * q0v * g0 + acc[a][1] * q1v * g1
              + acc[a][2] * q2v * g2 + acc[a][3] * q3v * g3;
      }
#pragma unroll
      for (int m = 1; m < 16; m <<= 1) {
#pragma unroll
        for (int a = 0; a < 4; ++a) {
          ss[a] += __shfl_xor(ss[a], m);
          sc[a] += __shfl_xor(sc[a], m);
        }
      }
      if (tc == 0) {
#pragma unroll
        for (int a = 0; a < 4; ++a) {
          const float n = fmaxf(sqrtf(ss[a]), 1e-12f);
          s_scores[j0 + a][h] = (8.f / n) * sc[a];
        }
      }
    }
  }
  __syncthreads();

  // ---- P5: masked softmax over K (48 tasks)
  if (tid < QT * NH_) {
    const int r = tid / NH_, h = tid % NH_;
    float s[K_]; float mx = -1e38f;
#pragma unroll
    for (int k = 0; k < K_; ++k) {
      float v = s_scores[r * K_ + k][h];
      if (s_mask[r * K_ + k] == 0.f) v = -1e30f;
      s[k] = v; mx = fmaxf(mx, v);
    }
    float sum = 0.f;
#pragma unroll
    for (int k = 0; k < K_; ++k) { const float pp = expf(s[k] - mx); s[k] = pp; sum += pp; }
    const float inv = 1.f / sum;
#pragma unroll
    for (int k = 0; k < K_; ++k) s_attn[r][h][k] = s[k] * inv;
  }
  __syncthreads();

  // ---- P6: xbar = attn-weighted X rows, then V-GEMM (2 chunks of 3 heads)
  for (int ch = 0; ch < 2; ++ch) {
    for (int o = tid; o < 24 * KVIN; o += 256) {
      const int rhl = o / KVIN, kk = o % KVIN;
      const int r = rhl / 3, h = ch * 3 + rhl % 3;
      const float* at = s_attn[r][h];
      float acc = 0.f;
#pragma unroll
      for (int k = 0; k < K_; ++k) acc += at[k] * s_X[r * K_ + k][kk];
      s_regB[rhl * XLD + kk] = acc;
    }
    __syncthreads();
    for (int o = tid; o < 24 * DH_; o += 256) {
      const int rhl = o >> 6, d = o & 63;
      const int r = rhl / 3, h = ch * 3 + rhl % 3;
      const float* xb = s_regB + rhl * XLD;
      const float* wv = Wkv + (size_t)INNER + h * DH_ + d;   // V columns
      float acc = 0.f;
      for (int kk = 0; kk < KVIN; ++kk) acc += xb[kk] * wv[(size_t)kk * (2 * INNER)];
      s_regA[r][h * DH_ + d] = acc;
    }
    __syncthreads();
  }

  // ---- P7: output projection (each thread: 1 row, 12 contiguous cols)
  {
    const int r  = tid >> 5;
    const int c0 = (tid & 31) * 12;
    float acc[12];
#pragma unroll
    for (int i = 0; i < 12; ++i) acc[i] = 0.f;
    for (int cc = 0; cc < INNER; ++cc) {
      const float av = s_regA[r][cc];
      const float4* wp = reinterpret_cast<const float4*>(Wout + (size_t)cc * INNER + c0);
      const float4 w0 = wp[0], w1 = wp[1], w2 = wp[2];
      acc[0] += av * w0.x; acc[1] += av * w0.y; acc[2]  += av * w0.z; acc[3]  += av * w0.w;
      acc[4] += av * w1.x; acc[5] += av * w1.y; acc[6]  += av * w1.z; acc[7]  += av * w1.w;
      acc[8] += av * w2.x; acc[9] += av * w2.y; acc[10] += av * w2.z; acc[11] += av * w2.w;
    }
    float* orow = out + ((size_t)b * HW_ + q0 + r) * INNER + c0;
#pragma unroll
    for (int i = 0; i < 12; ++i) orow[i] = acc[i];
  }
}

// ---------------------------------------------------------------------------
extern "C" void kernel_launch(void* const* d_in, const int* in_sizes, int n_in,
                              void* d_out, int out_size, void* d_ws, size_t ws_size,
                              hipStream_t stream) {
  (void)in_sizes; (void)n_in; (void)out_size; (void)ws_size;
  const float* feat_2d = (const float*)d_in[0];
  const float* feat_3d = (const float*)d_in[1];
  const float* proj_uv = (const float*)d_in[2];
  const float* img_uv  = (const float*)d_in[3];
  const float* ln_g    = (const float*)d_in[4];
  const float* q_g     = (const float*)d_in[5];
  const float* k_g     = (const float*)d_in[6];
  const float* Wq      = (const float*)d_in[7];
  const float* Wkv     = (const float*)d_in[8];
  const float* Wout    = (const float*)d_in[9];
  float* out   = (float*)d_out;
  int*  idx_ws = (int*)d_ws;   // B*HW*K int32 = 614,400 B

  knn_kernel<<<dim3(B_ * HW_ / 4), 256, 0, stream>>>(proj_uv, img_uv, idx_ws);
  fused_kernel<<<dim3(HW_ / QT, B_), 256, 0, stream>>>(
      feat_2d, feat_3d, img_uv, ln_g, q_g, k_g, Wq, Wkv, Wout, idx_ws, out);
}